// Round 10
// baseline (269.224 us; speedup 1.0000x reference)
//
#include <hip/hip_runtime.h>
#include <hip/hip_bf16.h>

#define KDIM 1024   // 2*ENC_H
#define HDIM 1024   // DEC_H
#define BM   64
#define SPART 65536

typedef __attribute__((ext_vector_type(8))) short bf16x8_t;
typedef __attribute__((ext_vector_type(16))) float f32x16_t;
typedef __attribute__((ext_vector_type(4))) float f32x4_t;
typedef __attribute__((ext_vector_type(4))) unsigned int u32x4_t;
typedef __attribute__((ext_vector_type(2))) unsigned int u32x2_t;

#define WAITVM(n) asm volatile("s_waitcnt vmcnt(" #n ")" ::: "memory")
#define MEMFENCE() asm volatile("" ::: "memory")

__device__ __forceinline__ unsigned int pack2bf(float a, float b) {
    union { float f; unsigned int u; } ua, ub;
    ua.f = a; ub.f = b;
    unsigned int ra = (ua.u + 0x7fffu + ((ua.u >> 16) & 1u)) >> 16;  // RNE
    unsigned int rb = (ub.u + 0x7fffu + ((ub.u >> 16) & 1u)) >> 16;
    return ra | (rb << 16);
}

__device__ __forceinline__ unsigned int cvtpk(float lo, float hi) {
    unsigned int r;
    asm("v_cvt_pk_bf16_f32 %0, %1, %2" : "=v"(r) : "v"(lo), "v"(hi));
    return r;
}

__device__ __forceinline__ void gload16(const void* g, void* l) {
    __builtin_amdgcn_global_load_lds(
        (const __attribute__((address_space(1))) void*)g,
        (__attribute__((address_space(3))) void*)l, 16, 0, 0);
}

// ---- kernel 1a: W_e -> bf16, fragment-order layout we_t[ks][h][16] ----
__global__ void cvt_we_k(const float* __restrict__ attn_w, unsigned short* __restrict__ we_t) {
    const int h = blockIdx.x;      // 1024
    const int t = threadIdx.x;     // 256
    const f32x4_t v = *(const f32x4_t*)(attn_w + (size_t)h * 2048 + 1024 + (size_t)t * 4);
    u32x2_t o;
    o[0] = pack2bf(v[0], v[1]);
    o[1] = pack2bf(v[2], v[3]);
    const int ks  = t >> 2;
    const int e15 = (t & 3) * 4;
    *(u32x2_t*)&we_t[(size_t)ks * 16384 + h * 16 + e15] = o;
}

// ---- kernel 1b: proj_s[b][h] = sum_d s[b,d] * attn_w[h, d]  (fp32) ----
__global__ void proj_s_k(const float* __restrict__ s, const float* __restrict__ attn_w,
                         float* __restrict__ ps) {
    const int h = (blockIdx.x * blockDim.x + threadIdx.x) >> 6;
    const int lane = threadIdx.x & 63;
    const float* wr = attn_w + (size_t)h * 2048;
    float w[16];
#pragma unroll
    for (int i = 0; i < 16; ++i) w[i] = wr[lane + 64 * i];
    for (int b = 0; b < 32; ++b) {
        const float* sr = s + (size_t)b * 1024;
        float a = 0.f;
#pragma unroll
        for (int i = 0; i < 16; ++i) a = fmaf(w[i], sr[lane + 64 * i], a);
#pragma unroll
        for (int off = 32; off >= 1; off >>= 1) a += __shfl_xor(a, off, 64);
        if (lane == 0) ps[b * 1024 + h] = a;
    }
}

// ---- kernel 2: fp32-glds GEMM + tanh + v-dot -> partial scores ----
// 2048 blocks (m_tile x hhalf), 512 thr = 8 waves all-MFMA.
// A: fp32 in 4-slot LDS ring (BK=64, 16 KB/slot), filled by global_load_lds
//    issued 2 kc ahead straight from enc (HBM read once); per-lane PRE-SWIZZLED
//    global source addr (c = cp ^ (r&15)) -> linear LDS dest, conflict-free reads.
// B: we_t fragment-order, depth-3 reg prefetch (L2).
// Per-kc barrier = counted WAITVM (reference glds is a full kc old -> ~free).
__launch_bounds__(512, 4)
__global__ void fused_main3_k(const float* __restrict__ enc,
                              const unsigned short* __restrict__ we_t,
                              const float* __restrict__ ps,
                              const float* __restrict__ vw,
                              float* __restrict__ scores_part) {
    __shared__ float lds_a[4 * 64 * 64];   // 4 slots x 64 rows x 64 f32 = 64 KB

    const int t = threadIdx.x;
    const int bid = blockIdx.x;
    const int xcd   = bid & 7;
    const int hhalf = (bid >> 3) & 1;              // siblings 8 apart -> same XCD
    const int m_swz = xcd * 128 + (bid >> 4);      // bijective over 1024 m-tiles
    const int m_base = m_swz * BM;
    const int bidx = m_swz >> 5;

    const int lane = t & 63;
    const int wid  = t >> 6;        // 0..7
    const int l31  = lane & 31;
    const int h5   = lane >> 5;
    const int habs = hhalf * 512 + wid * 64;

    // ---- glds staging: thread t covers rows {t>>4, 32+(t>>4)}, 16B chunk t&15.
    // LDS image: slot[r][cp] holds global chunk c = cp ^ (r&15)  (16B units, 16/row)
    const int gr = t >> 4;                       // 0..31
    const int gc = (t & 15) ^ (gr & 15);         // pre-swizzled global chunk
    const float* gbase0 = enc + (size_t)(m_base + gr) * KDIM + gc * 4;
    const float* gbase1 = gbase0 + (size_t)32 * KDIM;

    auto stageG = [&](int kc) {
        const float* g0 = gbase0 + kc * 64;
        const float* g1 = gbase1 + kc * 64;
        char* d = (char*)lds_a + (kc & 3) * 16384 + t * 16;   // wave-uniform + lane*16
        gload16(g0, d);
        gload16(g1, d + 8192);
    };

    // B: fragment-order; frag(g, nf) at btile + g*16384 + nf*512 (shorts)
    const unsigned short* btile = we_t + (size_t)(habs + l31) * 16 + h5 * 8;
    auto loadB = [&](int g, bf16x8_t* dst) {
        const unsigned short* bp = btile + (size_t)g * 16384;
        dst[0] = *(const bf16x8_t*)(bp);
        dst[1] = *(const bf16x8_t*)(bp + 512);
    };

    f32x16_t acc[2][2];
#pragma unroll
    for (int m = 0; m < 2; ++m)
#pragma unroll
        for (int nf = 0; nf < 2; ++nf)
#pragma unroll
            for (int r = 0; r < 16; ++r) acc[m][nf][r] = 0.f;

    bf16x8_t bbuf[4][2];

    // prologue: glds slots 0,1 (4 instrs) -> fence -> B g=0..2 (6 instrs)
    stageG(0);
    stageG(1);
    MEMFENCE();
    loadB(0, bbuf[0]);
    loadB(1, bbuf[1]);
    loadB(2, bbuf[2]);
    WAITVM(8);                        // slot0's 2 glds retired (younger: 2 glds + 6 B)
    __builtin_amdgcn_s_barrier();
    MEMFENCE();

    const int xr = l31 & 15;
    const int a0base = l31 * 256;          // byte offset of row l31
    const int a1base = (32 + l31) * 256;

#pragma unroll
    for (int kc = 0; kc < 16; ++kc) {
        const char* slotp = (const char*)lds_a + (kc & 3) * 16384;
#pragma unroll
        for (int ksl = 0; ksl < 4; ++ksl) {
            const int g = kc * 4 + ksl;
            if (g + 3 < 64) loadB(g + 3, bbuf[(g + 3) & 3]);   // depth-3 B prefetch (L2)

            // A frags: k-low chunk at cp0 = (ksl*4 + h5*2) ^ xr, k-high at cp0^1
            const int co = (((ksl << 2) + (h5 << 1)) ^ xr) << 4;
            const f32x4_t lo0 = *(const f32x4_t*)(slotp + a0base + co);
            const f32x4_t hi0 = *(const f32x4_t*)(slotp + a0base + (co ^ 16));
            const f32x4_t lo1 = *(const f32x4_t*)(slotp + a1base + co);
            const f32x4_t hi1 = *(const f32x4_t*)(slotp + a1base + (co ^ 16));
            union { u32x4_t u; bf16x8_t b; } ca0, ca1;
            ca0.u[0] = cvtpk(lo0[0], lo0[1]);
            ca0.u[1] = cvtpk(lo0[2], lo0[3]);
            ca0.u[2] = cvtpk(hi0[0], hi0[1]);
            ca0.u[3] = cvtpk(hi0[2], hi0[3]);
            ca1.u[0] = cvtpk(lo1[0], lo1[1]);
            ca1.u[1] = cvtpk(lo1[2], lo1[3]);
            ca1.u[2] = cvtpk(hi1[0], hi1[1]);
            ca1.u[3] = cvtpk(hi1[2], hi1[3]);

            const bf16x8_t* bfr = bbuf[g & 3];
            __builtin_amdgcn_s_setprio(1);
            acc[0][0] = __builtin_amdgcn_mfma_f32_32x32x16_bf16(ca0.b, bfr[0], acc[0][0], 0, 0, 0);
            acc[1][0] = __builtin_amdgcn_mfma_f32_32x32x16_bf16(ca1.b, bfr[0], acc[1][0], 0, 0, 0);
            acc[0][1] = __builtin_amdgcn_mfma_f32_32x32x16_bf16(ca0.b, bfr[1], acc[0][1], 0, 0, 0);
            acc[1][1] = __builtin_amdgcn_mfma_f32_32x32x16_bf16(ca1.b, bfr[1], acc[1][1], 0, 0, 0);
            __builtin_amdgcn_s_setprio(0);
        }
        MEMFENCE();
        if (kc + 2 < 16) stageG(kc + 2);    // refill slot (kc+2)&3 (read finished at kc-2)
        if (kc < 15) {
            // counted wait: slot kc+1's glds (issued during kc-1) retired.
            // younger ops: this kc's 8 B-loads + stageG(kc+2)'s 2 glds (if issued).
            if (kc == 14) WAITVM(8); else WAITVM(10);
            __builtin_amdgcn_s_barrier();
            MEMFENCE();
        }
    }

    // ---- epilogue: tanh(ps + pe) * v, per-lane partials over C-rows ----
    float sc2[2][16];
#pragma unroll
    for (int m = 0; m < 2; ++m)
#pragma unroll
        for (int r = 0; r < 16; ++r) sc2[m][r] = 0.f;

#pragma unroll
    for (int nf = 0; nf < 2; ++nf) {
        const int h = habs + nf * 32 + l31;
        const float pv = ps[bidx * 1024 + h];
        const float vv = vw[h];
#pragma unroll
        for (int m = 0; m < 2; ++m)
#pragma unroll
            for (int r = 0; r < 16; ++r) {
                const float x = acc[m][nf][r] + pv;
                const float e = __expf(2.0f * x);
                const float th = 1.0f - __fdividef(2.0f, e + 1.0f);
                sc2[m][r] = fmaf(vv, th, sc2[m][r]);
            }
    }

#pragma unroll
    for (int off = 1; off < 32; off <<= 1)
#pragma unroll
        for (int m = 0; m < 2; ++m)
#pragma unroll
            for (int r = 0; r < 16; ++r)
                sc2[m][r] += __shfl_xor(sc2[m][r], off, 64);

    __syncthreads();   // loop done; reuse LDS as partials buffer
    float* slds = (float*)lds_a;   // [8 waves][64 rows]
    if (l31 == 0) {
#pragma unroll
        for (int m = 0; m < 2; ++m)
#pragma unroll
            for (int r = 0; r < 16; ++r) {
                const int row = m * 32 + (r & 3) + 8 * (r >> 2) + 4 * h5;
                slds[wid * 64 + row] = sc2[m][r];
            }
    }
    __syncthreads();
    if (t < 64) {
        float v = 0.f;
#pragma unroll
        for (int w = 0; w < 8; ++w) v += slds[w * 64 + t];
        scores_part[(size_t)hhalf * SPART + m_base + t] = v;
    }
}

// ---- kernel 3: row softmax over S=2048 per batch (sums the two h-half partials) ----
__global__ void softmax_k(const float* __restrict__ sc, float* __restrict__ out) {
    const int b = blockIdx.x;
    const int t = threadIdx.x;
    const int lane = t & 63;
    const int w = t >> 6;
    const float* r0 = sc + (size_t)b * 2048;
    const float* r1 = sc + SPART + (size_t)b * 2048;
    float x[8];
#pragma unroll
    for (int i = 0; i < 8; ++i) x[i] = r0[i * 256 + t] + r1[i * 256 + t];
    float m = x[0];
#pragma unroll
    for (int i = 1; i < 8; ++i) m = fmaxf(m, x[i]);
#pragma unroll
    for (int off = 32; off >= 1; off >>= 1) m = fmaxf(m, __shfl_xor(m, off, 64));
    __shared__ float sred[4];
    __shared__ float sred2[4];
    if (lane == 0) sred[w] = m;
    __syncthreads();
    m = fmaxf(fmaxf(sred[0], sred[1]), fmaxf(sred[2], sred[3]));
    float ssum = 0.f;
#pragma unroll
    for (int i = 0; i < 8; ++i) { x[i] = expf(x[i] - m); ssum += x[i]; }
#pragma unroll
    for (int off = 32; off >= 1; off >>= 1) ssum += __shfl_xor(ssum, off, 64);
    if (lane == 0) sred2[w] = ssum;
    __syncthreads();
    const float inv = 1.0f / (sred2[0] + sred2[1] + sred2[2] + sred2[3]);
#pragma unroll
    for (int i = 0; i < 8; ++i) out[(size_t)b * 2048 + i * 256 + t] = x[i] * inv;
}

extern "C" void kernel_launch(void* const* d_in, const int* in_sizes, int n_in,
                              void* d_out, int out_size, void* d_ws, size_t ws_size,
                              hipStream_t stream) {
    const float* s      = (const float*)d_in[0];
    const float* enc    = (const float*)d_in[1];
    const float* attn_w = (const float*)d_in[2];
    const float* vw     = (const float*)d_in[3];
    float* out = (float*)d_out;

    unsigned short* we = (unsigned short*)d_ws;                             // 2 MB bf16 we_t
    float* ps     = (float*)((char*)d_ws + (2u << 20));                     // 128 KB proj_s
    float* scores = (float*)((char*)d_ws + (2u << 20) + (128u << 10));      // 512 KB partials

    cvt_we_k<<<1024, 256, 0, stream>>>(attn_w, we);
    proj_s_k<<<256, 256, 0, stream>>>(s, attn_w, ps);
    fused_main3_k<<<2048, 512, 0, stream>>>(enc, we, ps, vw, scores);
    softmax_k<<<32, 256, 0, stream>>>(scores, out);
}

// Round 11
// 229.395 us; speedup vs baseline: 1.1736x; 1.1736x over previous
//
#include <hip/hip_runtime.h>
#include <hip/hip_bf16.h>

#define KDIM 1024   // 2*ENC_H
#define HDIM 1024   // DEC_H
#define SPART 65536

typedef __attribute__((ext_vector_type(8))) short bf16x8_t;
typedef __attribute__((ext_vector_type(16))) float f32x16_t;
typedef __attribute__((ext_vector_type(4))) float f32x4_t;
typedef __attribute__((ext_vector_type(4))) unsigned int u32x4_t;
typedef __attribute__((ext_vector_type(2))) unsigned int u32x2_t;

#define WAITVM(n) asm volatile("s_waitcnt vmcnt(" #n ")" ::: "memory")
#define MEMFENCE() asm volatile("" ::: "memory")

__device__ __forceinline__ unsigned int pack2bf(float a, float b) {
    union { float f; unsigned int u; } ua, ub;
    ua.f = a; ub.f = b;
    unsigned int ra = (ua.u + 0x7fffu + ((ua.u >> 16) & 1u)) >> 16;  // RNE
    unsigned int rb = (ub.u + 0x7fffu + ((ub.u >> 16) & 1u)) >> 16;
    return ra | (rb << 16);
}

__device__ __forceinline__ unsigned int cvtpk(float lo, float hi) {
    unsigned int r;
    asm("v_cvt_pk_bf16_f32 %0, %1, %2" : "=v"(r) : "v"(lo), "v"(hi));
    return r;
}

__device__ __forceinline__ void gload16(const void* g, void* l) {
    __builtin_amdgcn_global_load_lds(
        (const __attribute__((address_space(1))) void*)g,
        (__attribute__((address_space(3))) void*)l, 16, 0, 0);
}

// ---- kernel 1a: W_e -> bf16, fragment-order layout we_t[ks][h][16] ----
__global__ void cvt_we_k(const float* __restrict__ attn_w, unsigned short* __restrict__ we_t) {
    const int h = blockIdx.x;      // 1024
    const int t = threadIdx.x;     // 256
    const f32x4_t v = *(const f32x4_t*)(attn_w + (size_t)h * 2048 + 1024 + (size_t)t * 4);
    u32x2_t o;
    o[0] = pack2bf(v[0], v[1]);
    o[1] = pack2bf(v[2], v[3]);
    const int ks  = t >> 2;
    const int e15 = (t & 3) * 4;
    *(u32x2_t*)&we_t[(size_t)ks * 16384 + h * 16 + e15] = o;
}

// ---- kernel 1b: proj_s[b][h] = sum_d s[b,d] * attn_w[h, d]  (fp32) ----
__global__ void proj_s_k(const float* __restrict__ s, const float* __restrict__ attn_w,
                         float* __restrict__ ps) {
    const int h = (blockIdx.x * blockDim.x + threadIdx.x) >> 6;
    const int lane = threadIdx.x & 63;
    const float* wr = attn_w + (size_t)h * 2048;
    float w[16];
#pragma unroll
    for (int i = 0; i < 16; ++i) w[i] = wr[lane + 64 * i];
    for (int b = 0; b < 32; ++b) {
        const float* sr = s + (size_t)b * 1024;
        float a = 0.f;
#pragma unroll
        for (int i = 0; i < 16; ++i) a = fmaf(w[i], sr[lane + 64 * i], a);
#pragma unroll
        for (int off = 32; off >= 1; off >>= 1) a += __shfl_xor(a, off, 64);
        if (lane == 0) ps[b * 1024 + h] = a;
    }
}

// ---- kernel 2: BM=128 fp32-glds GEMM + tanh + v-dot -> partial scores ----
// 1024 blocks (512 m-tiles x 2 hhalf), 512 thr = 8 waves, 1 block/CU.
// A: fp32 2-slot LDS ring (128 rows x BK=64 = 32 KB/slot), global_load_lds
//    (4/thread) issued at kc-top -> full-kc HBM cover; pre-swizzled source.
// B: we_t fragment-order, depth-3 reg prefetch; reuse 4 (acc[4][2] = 128 AGPR).
// Per-kc: uniform counted WAITVM(6) + raw barrier (glds a full kc old).
__launch_bounds__(512, 2)
__global__ void fused_main4_k(const float* __restrict__ enc,
                              const unsigned short* __restrict__ we_t,
                              const float* __restrict__ ps,
                              const float* __restrict__ vw,
                              float* __restrict__ scores_part) {
    __shared__ float lds_a[2 * 128 * 64];   // 2 slots x 128 rows x 64 f32 = 64 KB

    const int t = threadIdx.x;
    const int bid = blockIdx.x;
    const int xcd   = bid & 7;
    const int hhalf = (bid >> 3) & 1;              // siblings 8 apart -> same XCD
    const int m_swz = xcd * 64 + (bid >> 4);       // bijective over 512 m-tiles
    const int m_base = m_swz * 128;
    const int bidx = m_swz >> 4;                   // batch (16 tiles of 128 rows each)

    const int lane = t & 63;
    const int wid  = t >> 6;        // 0..7
    const int l31  = lane & 31;
    const int h5   = lane >> 5;
    const int habs = hhalf * 512 + wid * 64;

    // ---- glds staging: thread t covers rows {gr, gr+32, gr+64, gr+96}, chunk t&15.
    // LDS image: slot[r][cp] holds global 16B chunk c = cp ^ (r&15); rows share r&15.
    const int gr = t >> 4;                       // 0..31
    const int gc = (t & 15) ^ (gr & 15);         // pre-swizzled global chunk
    const float* gb = enc + (size_t)(m_base + gr) * KDIM + gc * 4;

    auto stageG = [&](int kc) {
        const float* g = gb + kc * 64;
        char* d = (char*)lds_a + (kc & 1) * 32768 + t * 16;   // wave-uniform + lane*16
        gload16(g,                  d);
        gload16(g + 32 * KDIM,      d + 8192);
        gload16(g + 64 * KDIM,      d + 16384);
        gload16(g + 96 * KDIM,      d + 24576);
    };

    // B: fragment-order; frag(g, nf) at btile + g*16384 + nf*512 (shorts)
    const unsigned short* btile = we_t + (size_t)(habs + l31) * 16 + h5 * 8;
    auto loadB = [&](int g, bf16x8_t* dst) {
        const unsigned short* bp = btile + (size_t)g * 16384;
        dst[0] = *(const bf16x8_t*)(bp);
        dst[1] = *(const bf16x8_t*)(bp + 512);
    };

    f32x16_t acc[4][2];
#pragma unroll
    for (int m = 0; m < 4; ++m)
#pragma unroll
        for (int nf = 0; nf < 2; ++nf)
#pragma unroll
            for (int r = 0; r < 16; ++r) acc[m][nf][r] = 0.f;

    bf16x8_t bbuf[4][2];

    // prologue: glds slot 0 (4 instrs) -> fence -> B g=0..2 (6 instrs)
    stageG(0);
    MEMFENCE();
    loadB(0, bbuf[0]);
    loadB(1, bbuf[1]);
    loadB(2, bbuf[2]);
    WAITVM(6);                        // slot0's 4 glds retired (6 B younger)
    __builtin_amdgcn_s_barrier();

    const int xr = l31 & 15;

#pragma unroll
    for (int kc = 0; kc < 16; ++kc) {
        if (kc + 1 < 16) stageG(kc + 1);   // into opposite slot; full-kc cover
        MEMFENCE();
        const char* slotp = (const char*)lds_a + (kc & 1) * 32768;
#pragma unroll
        for (int ksl = 0; ksl < 4; ++ksl) {
            const int g = kc * 4 + ksl;
            if (g + 3 < 64) loadB(g + 3, bbuf[(g + 3) & 3]);   // depth-3 B prefetch (L2)

            // A frags: chunk c0 = ksl*4 + h5*2, stored at (c0^xr), pair at ^1
            const int co = (((ksl << 2) + (h5 << 1)) ^ xr) << 4;
            union { u32x4_t u; bf16x8_t b; } ca[4];
#pragma unroll
            for (int mi = 0; mi < 4; ++mi) {
                const char* rowp = slotp + mi * 8192 + l31 * 256;
                const f32x4_t lo = *(const f32x4_t*)(rowp + co);
                const f32x4_t hi = *(const f32x4_t*)(rowp + (co ^ 16));
                ca[mi].u[0] = cvtpk(lo[0], lo[1]);
                ca[mi].u[1] = cvtpk(lo[2], lo[3]);
                ca[mi].u[2] = cvtpk(hi[0], hi[1]);
                ca[mi].u[3] = cvtpk(hi[2], hi[3]);
            }
            const bf16x8_t* bfr = bbuf[g & 3];
            __builtin_amdgcn_s_setprio(1);
#pragma unroll
            for (int mi = 0; mi < 4; ++mi) {
                acc[mi][0] = __builtin_amdgcn_mfma_f32_32x32x16_bf16(ca[mi].b, bfr[0], acc[mi][0], 0, 0, 0);
                acc[mi][1] = __builtin_amdgcn_mfma_f32_32x32x16_bf16(ca[mi].b, bfr[1], acc[mi][1], 0, 0, 0);
            }
            __builtin_amdgcn_s_setprio(0);
        }
        if (kc + 1 < 16) {
            WAITVM(6);                      // slot kc+1's glds retired (3 loadB younger)
            __builtin_amdgcn_s_barrier();
        }
    }

    // ---- epilogue: tanh(ps + pe) * v, per-lane partials over C-rows ----
    float sc2[4][16];
#pragma unroll
    for (int m = 0; m < 4; ++m)
#pragma unroll
        for (int r = 0; r < 16; ++r) sc2[m][r] = 0.f;

#pragma unroll
    for (int nf = 0; nf < 2; ++nf) {
        const int h = habs + nf * 32 + l31;
        const float pv = ps[bidx * 1024 + h];
        const float vv = vw[h];
#pragma unroll
        for (int m = 0; m < 4; ++m)
#pragma unroll
            for (int r = 0; r < 16; ++r) {
                const float x = acc[m][nf][r] + pv;
                const float e = __expf(2.0f * x);
                const float th = 1.0f - __fdividef(2.0f, e + 1.0f);
                sc2[m][r] = fmaf(vv, th, sc2[m][r]);
            }
    }

    // reduce over the 32-lane column group (h dimension); h5 preserved
#pragma unroll
    for (int off = 1; off < 32; off <<= 1)
#pragma unroll
        for (int m = 0; m < 4; ++m)
#pragma unroll
            for (int r = 0; r < 16; ++r)
                sc2[m][r] += __shfl_xor(sc2[m][r], off, 64);

    __syncthreads();   // loop done; reuse LDS as partials buffer
    float* slds = (float*)lds_a;   // [8 waves][128 rows]
    if (l31 == 0) {
#pragma unroll
        for (int m = 0; m < 4; ++m)
#pragma unroll
            for (int r = 0; r < 16; ++r) {
                const int row = m * 32 + (r & 3) + 8 * (r >> 2) + 4 * h5;
                slds[wid * 128 + row] = sc2[m][r];
            }
    }
    __syncthreads();
    if (t < 128) {
        float v = 0.f;
#pragma unroll
        for (int w = 0; w < 8; ++w) v += slds[w * 128 + t];
        scores_part[(size_t)hhalf * SPART + m_base + t] = v;
    }
}

// ---- kernel 3: row softmax over S=2048 per batch (sums the two h-half partials) ----
__global__ void softmax_k(const float* __restrict__ sc, float* __restrict__ out) {
    const int b = blockIdx.x;
    const int t = threadIdx.x;
    const int lane = t & 63;
    const int w = t >> 6;
    const float* r0 = sc + (size_t)b * 2048;
    const float* r1 = sc + SPART + (size_t)b * 2048;
    float x[8];
#pragma unroll
    for (int i = 0; i < 8; ++i) x[i] = r0[i * 256 + t] + r1[i * 256 + t];
    float m = x[0];
#pragma unroll
    for (int i = 1; i < 8; ++i) m = fmaxf(m, x[i]);
#pragma unroll
    for (int off = 32; off >= 1; off >>= 1) m = fmaxf(m, __shfl_xor(m, off, 64));
    __shared__ float sred[4];
    __shared__ float sred2[4];
    if (lane == 0) sred[w] = m;
    __syncthreads();
    m = fmaxf(fmaxf(sred[0], sred[1]), fmaxf(sred[2], sred[3]));
    float ssum = 0.f;
#pragma unroll
    for (int i = 0; i < 8; ++i) { x[i] = expf(x[i] - m); ssum += x[i]; }
#pragma unroll
    for (int off = 32; off >= 1; off >>= 1) ssum += __shfl_xor(ssum, off, 64);
    if (lane == 0) sred2[w] = ssum;
    __syncthreads();
    const float inv = 1.0f / (sred2[0] + sred2[1] + sred2[2] + sred2[3]);
#pragma unroll
    for (int i = 0; i < 8; ++i) out[(size_t)b * 2048 + i * 256 + t] = x[i] * inv;
}

extern "C" void kernel_launch(void* const* d_in, const int* in_sizes, int n_in,
                              void* d_out, int out_size, void* d_ws, size_t ws_size,
                              hipStream_t stream) {
    const float* s      = (const float*)d_in[0];
    const float* enc    = (const float*)d_in[1];
    const float* attn_w = (const float*)d_in[2];
    const float* vw     = (const float*)d_in[3];
    float* out = (float*)d_out;

    unsigned short* we = (unsigned short*)d_ws;                             // 2 MB bf16 we_t
    float* ps     = (float*)((char*)d_ws + (2u << 20));                     // 128 KB proj_s
    float* scores = (float*)((char*)d_ws + (2u << 20) + (128u << 10));      // 512 KB partials

    cvt_we_k<<<1024, 256, 0, stream>>>(attn_w, we);
    proj_s_k<<<256, 256, 0, stream>>>(s, attn_w, ps);
    fused_main4_k<<<1024, 512, 0, stream>>>(enc, we, ps, vw, scores);
    softmax_k<<<32, 256, 0, stream>>>(scores, out);
}